// Round 1
// baseline (229.143 us; speedup 1.0000x reference)
//
#include <hip/hip_runtime.h>

// SSIM loss, fp32, x/y: (32,3,512,512), scalar mean output.
// Strategy: wave-per-column-tile sliding window.
//   - 64 lanes load 64 consecutive (padded) columns; horizontal 3-tap sums of
//     {x, y, x^2, y^2, xy} via __shfl_up/__shfl_down (lanes 1..62 produce output).
//   - Vertical 3-tap via rolling 3-row register window -> each input element is
//     loaded from global exactly once per strip (plus 2 halo rows).
//   - Reflect padding resolved on the index: -1 -> 1, 512 -> 510.
//   - Block partial sums -> d_ws, then a 1-block reduce kernel writes the mean.

#define IMG_H 512
#define IMG_W 512
#define N_PLANES 96            // 32 * 3
#define ROWS_PER_WAVE 64
#define COLS_PER_WAVE 62       // 64 lanes, 2 halo
#define N_TILES 9              // ceil(512 / 62)
#define HALVES 2               // block = 4 waves x 64 rows = 256 rows; 512/256 = 2
#define N_MAIN_BLOCKS (N_PLANES * N_TILES * HALVES)   // 1728
#define TOTAL_ELEMS 25165824.0f                        // 32*3*512*512

__device__ __forceinline__ int reflect512(int i) {
    i = i < 0 ? -i : i;
    return i > (IMG_H - 1) ? (2 * (IMG_H - 1) - i) : i;
}

struct Row5 { float x, y, xx, yy, xy; };

// Load one padded row for this lane's column and build horizontal 3-tap sums.
__device__ __forceinline__ Row5 load_row(const float* __restrict__ px,
                                         const float* __restrict__ py,
                                         int r, int colr) {
    const int rr = reflect512(r);
    const float xv = px[rr * IMG_W + colr];
    const float yv = py[rr * IMG_W + colr];
    const float xm = __shfl_up(xv, 1);    // lane-1's column (col-1)
    const float xp = __shfl_down(xv, 1);  // lane+1's column (col+1)
    const float ym = __shfl_up(yv, 1);
    const float yp = __shfl_down(yv, 1);
    Row5 h;
    h.x  = xm + xv + xp;
    h.y  = ym + yv + yp;
    h.xx = fmaf(xm, xm, fmaf(xv, xv, xp * xp));
    h.yy = fmaf(ym, ym, fmaf(yv, yv, yp * yp));
    h.xy = fmaf(xm, ym, fmaf(xv, yv, xp * yp));
    return h;
}

__global__ __launch_bounds__(256, 4)
void ssim_main_kernel(const float* __restrict__ x, const float* __restrict__ y,
                      float* __restrict__ partials) {
    const int blk   = blockIdx.x;
    const int plane = blk / (N_TILES * HALVES);
    const int rem   = blk % (N_TILES * HALVES);
    const int tile  = rem / HALVES;
    const int half  = rem % HALVES;
    const int wave  = threadIdx.x >> 6;
    const int lane  = threadIdx.x & 63;

    const int c0   = tile * COLS_PER_WAVE;
    const int col  = c0 - 1 + lane;         // output column for this lane
    const int colr = reflect512(col);       // column actually loaded
    const int r0   = (half * 4 + wave) * ROWS_PER_WAVE;

    const float* px = x + (size_t)plane * (IMG_H * IMG_W);
    const float* py = y + (size_t)plane * (IMG_H * IMG_W);

    // lanes 0 and 63 are halo; last tile has columns past 511
    const bool valid = (lane >= 1) && (lane <= COLS_PER_WAVE) && (col < IMG_W);

    Row5 h0 = load_row(px, py, r0 - 1, colr);
    Row5 h1 = load_row(px, py, r0,     colr);

    const float C1v  = 0.0001f;   // 0.01^2
    const float C2v  = 0.0009f;   // 0.03^2
    const float inv9 = 1.0f / 9.0f;

    float acc = 0.0f;
    for (int r = r0; r < r0 + ROWS_PER_WAVE; ++r) {
        Row5 h2 = load_row(px, py, r + 1, colr);

        const float sx  = h0.x  + h1.x  + h2.x;
        const float sy  = h0.y  + h1.y  + h2.y;
        const float sxx = h0.xx + h1.xx + h2.xx;
        const float syy = h0.yy + h1.yy + h2.yy;
        const float sxy = h0.xy + h1.xy + h2.xy;

        const float mux   = sx * inv9;
        const float muy   = sy * inv9;
        const float mux2  = mux * mux;
        const float muy2  = muy * muy;
        const float muxy  = mux * muy;
        const float sigx  = fmaf(sxx, inv9, -mux2);
        const float sigy  = fmaf(syy, inv9, -muy2);
        const float sigxy = fmaf(sxy, inv9, -muxy);

        const float nume = (2.0f * muxy + C1v) * (2.0f * sigxy + C2v);
        const float deno = (mux2 + muy2 + C1v) * (sigx + sigy + C2v);
        // v = (1 - n/d) / 2, clipped to [0,1]; v_rcp_f32 is ~1ulp, fine here
        float v = fmaf(nume, -__builtin_amdgcn_rcpf(deno), 1.0f) * 0.5f;
        v = fminf(fmaxf(v, 0.0f), 1.0f);
        acc += v;

        h0 = h1;
        h1 = h2;
    }

    if (!valid) acc = 0.0f;

    #pragma unroll
    for (int off = 32; off > 0; off >>= 1)
        acc += __shfl_down(acc, off);

    __shared__ float wave_sums[4];
    if (lane == 0) wave_sums[wave] = acc;
    __syncthreads();
    if (threadIdx.x == 0)
        partials[blk] = wave_sums[0] + wave_sums[1] + wave_sums[2] + wave_sums[3];
}

__global__ void ssim_reduce_kernel(const float* __restrict__ partials,
                                   float* __restrict__ out) {
    float acc = 0.0f;
    for (int i = threadIdx.x; i < N_MAIN_BLOCKS; i += 256)
        acc += partials[i];
    #pragma unroll
    for (int off = 32; off > 0; off >>= 1)
        acc += __shfl_down(acc, off);
    __shared__ float wave_sums[4];
    const int wave = threadIdx.x >> 6;
    const int lane = threadIdx.x & 63;
    if (lane == 0) wave_sums[wave] = acc;
    __syncthreads();
    if (threadIdx.x == 0)
        out[0] = (wave_sums[0] + wave_sums[1] + wave_sums[2] + wave_sums[3])
                 * (1.0f / TOTAL_ELEMS);
}

extern "C" void kernel_launch(void* const* d_in, const int* in_sizes, int n_in,
                              void* d_out, int out_size, void* d_ws, size_t ws_size,
                              hipStream_t stream) {
    const float* x = (const float*)d_in[0];
    const float* y = (const float*)d_in[1];
    float* out      = (float*)d_out;
    float* partials = (float*)d_ws;   // N_MAIN_BLOCKS floats, written (not accumulated)

    ssim_main_kernel<<<N_MAIN_BLOCKS, 256, 0, stream>>>(x, y, partials);
    ssim_reduce_kernel<<<1, 256, 0, stream>>>(partials, out);
}

// Round 2
// 217.481 us; speedup vs baseline: 1.0536x; 1.0536x over previous
//
#include <hip/hip_runtime.h>

// SSIM loss, fp32, x/y: (32,3,512,512), scalar mean output.
// R2: float4-per-lane sliding window.
//   - Wave covers a 256-column tile: lane L loads cols [c0+4L, c0+4L+3] as one
//     global_load_dwordx4 per input per row. Horizontal 3-tap needs only the
//     neighbors' edge elements: 2 shuffles per input + predicated scalar halo
//     loads on lanes 0/63 (tile edges, reflect-resolved).
//   - Vertical 3-tap via rolling 3-row register window (h0,h1,h2), with raw
//     loads for row r+2 issued one full iteration ahead (software prefetch).
//   - 512 cols = 2 tiles; rows split into 16-row wave strips -> 6144 waves.
//   - Block partials -> d_ws, 1-block reduce writes the mean.

#define IMG_H 512
#define IMG_W 512
#define N_PLANES 96                    // 32 * 3
#define TILE_W 256
#define N_TILES 2
#define RPW 16                         // rows per wave
#define WAVES_PER_BLOCK 4
#define ROWS_PER_BLOCK (RPW * WAVES_PER_BLOCK)          // 64
#define BLOCKS_PER_TILE (IMG_H / ROWS_PER_BLOCK)        // 8
#define N_MAIN_BLOCKS (N_PLANES * N_TILES * BLOCKS_PER_TILE)  // 1536
#define TOTAL_ELEMS 25165824.0f        // 32*3*512*512

__device__ __forceinline__ int reflect512(int i) {
    i = i < 0 ? -i : i;
    return i > (IMG_H - 1) ? (2 * (IMG_H - 1) - i) : i;
}

struct Raw {
    float4 xv, yv;   // this lane's 4 columns
    float  xh, yh;   // halo scalar (lane 0: col c0-1, lane 63: col c0+256)
};

struct H {           // horizontal 3-tap sums for this lane's 4 output columns
    float x[4], y[4], xx[4], yy[4], xy[4];
};

__device__ __forceinline__ Raw load_row(const float* __restrict__ px,
                                        const float* __restrict__ py,
                                        int r, int vidx, int lane,
                                        int lh, int rh) {
    const int rr = reflect512(r);
    const size_t rowb = (size_t)rr * IMG_W;
    Raw o;
    o.xv = ((const float4*)(px + rowb))[vidx];
    o.yv = ((const float4*)(py + rowb))[vidx];
    o.xh = 0.0f; o.yh = 0.0f;
    if (lane == 0 || lane == 63) {
        const int hc = (lane == 0) ? lh : rh;
        o.xh = px[rowb + hc];
        o.yh = py[rowb + hc];
    }
    return o;
}

__device__ __forceinline__ H build_h(const Raw& rw, int lane) {
    // Neighbor edge elements via shuffle; boundary lanes use their halo loads.
    float xm = __shfl_up(rw.xv.w, 1);
    float ym = __shfl_up(rw.yv.w, 1);
    float xp = __shfl_down(rw.xv.x, 1);
    float yp = __shfl_down(rw.yv.x, 1);
    if (lane == 0)  { xm = rw.xh; ym = rw.yh; }
    if (lane == 63) { xp = rw.xh; yp = rw.yh; }

    const float x6[6] = { xm, rw.xv.x, rw.xv.y, rw.xv.z, rw.xv.w, xp };
    const float y6[6] = { ym, rw.yv.x, rw.yv.y, rw.yv.z, rw.yv.w, yp };

    float xx6[6], yy6[6], xy6[6];
    #pragma unroll
    for (int i = 0; i < 6; ++i) {
        xx6[i] = x6[i] * x6[i];
        yy6[i] = y6[i] * y6[i];
        xy6[i] = x6[i] * y6[i];
    }
    H h;
    #pragma unroll
    for (int j = 0; j < 4; ++j) {
        h.x[j]  = x6[j]  + x6[j+1]  + x6[j+2];
        h.y[j]  = y6[j]  + y6[j+1]  + y6[j+2];
        h.xx[j] = xx6[j] + xx6[j+1] + xx6[j+2];
        h.yy[j] = yy6[j] + yy6[j+1] + yy6[j+2];
        h.xy[j] = xy6[j] + xy6[j+1] + xy6[j+2];
    }
    return h;
}

__global__ __launch_bounds__(256, 4)
void ssim_main_kernel(const float* __restrict__ x, const float* __restrict__ y,
                      float* __restrict__ partials) {
    const int blk   = blockIdx.x;
    const int plane = blk / (N_TILES * BLOCKS_PER_TILE);
    const int rem   = blk % (N_TILES * BLOCKS_PER_TILE);
    const int tile  = rem / BLOCKS_PER_TILE;
    const int rblk  = rem % BLOCKS_PER_TILE;
    const int wave  = threadIdx.x >> 6;
    const int lane  = threadIdx.x & 63;

    const int c0   = tile * TILE_W;
    const int vidx = (c0 >> 2) + lane;                 // float4 index within row
    const int lh   = reflect512(c0 - 1);               // left halo column
    const int rh   = reflect512(c0 + TILE_W);          // right halo column
    const int r0   = (rblk * WAVES_PER_BLOCK + wave) * RPW;

    const float* px = x + (size_t)plane * (IMG_H * IMG_W);
    const float* py = y + (size_t)plane * (IMG_H * IMG_W);

    const float C1v  = 0.0001f;   // 0.01^2
    const float C2v  = 0.0009f;   // 0.03^2
    const float inv9 = 1.0f / 9.0f;

    Raw ra = load_row(px, py, r0 - 1, vidx, lane, lh, rh);
    Raw rb = load_row(px, py, r0,     vidx, lane, lh, rh);
    Raw rc = load_row(px, py, r0 + 1, vidx, lane, lh, rh);
    H h0 = build_h(ra, lane);
    H h1 = build_h(rb, lane);

    float acc = 0.0f;
    for (int i = 0; i < RPW; ++i) {
        // Prefetch the row needed two iterations from now (reflect keeps the
        // address in-bounds even past the image; last prefetch is unused).
        Raw rd = load_row(px, py, r0 + 2 + i, vidx, lane, lh, rh);

        H h2 = build_h(rc, lane);

        #pragma unroll
        for (int j = 0; j < 4; ++j) {
            const float sx  = h0.x[j]  + h1.x[j]  + h2.x[j];
            const float sy  = h0.y[j]  + h1.y[j]  + h2.y[j];
            const float sxx = h0.xx[j] + h1.xx[j] + h2.xx[j];
            const float syy = h0.yy[j] + h1.yy[j] + h2.yy[j];
            const float sxy = h0.xy[j] + h1.xy[j] + h2.xy[j];

            const float mux   = sx * inv9;
            const float muy   = sy * inv9;
            const float mux2  = mux * mux;
            const float muy2  = muy * muy;
            const float muxy  = mux * muy;
            const float sigx  = fmaf(sxx, inv9, -mux2);
            const float sigy  = fmaf(syy, inv9, -muy2);
            const float sigxy = fmaf(sxy, inv9, -muxy);

            const float nume = (2.0f * muxy + C1v) * (2.0f * sigxy + C2v);
            const float deno = (mux2 + muy2 + C1v) * (sigx + sigy + C2v);
            float v = fmaf(nume, -__builtin_amdgcn_rcpf(deno), 1.0f) * 0.5f;
            v = fminf(fmaxf(v, 0.0f), 1.0f);
            acc += v;
        }

        h0 = h1;
        h1 = h2;
        rc = rd;
    }

    #pragma unroll
    for (int off = 32; off > 0; off >>= 1)
        acc += __shfl_down(acc, off);

    __shared__ float wave_sums[WAVES_PER_BLOCK];
    if (lane == 0) wave_sums[wave] = acc;
    __syncthreads();
    if (threadIdx.x == 0)
        partials[blk] = wave_sums[0] + wave_sums[1] + wave_sums[2] + wave_sums[3];
}

__global__ void ssim_reduce_kernel(const float* __restrict__ partials,
                                   float* __restrict__ out) {
    float acc = 0.0f;
    for (int i = threadIdx.x; i < N_MAIN_BLOCKS; i += 256)
        acc += partials[i];
    #pragma unroll
    for (int off = 32; off > 0; off >>= 1)
        acc += __shfl_down(acc, off);
    __shared__ float wave_sums[4];
    const int wave = threadIdx.x >> 6;
    const int lane = threadIdx.x & 63;
    if (lane == 0) wave_sums[wave] = acc;
    __syncthreads();
    if (threadIdx.x == 0)
        out[0] = (wave_sums[0] + wave_sums[1] + wave_sums[2] + wave_sums[3])
                 * (1.0f / TOTAL_ELEMS);
}

extern "C" void kernel_launch(void* const* d_in, const int* in_sizes, int n_in,
                              void* d_out, int out_size, void* d_ws, size_t ws_size,
                              hipStream_t stream) {
    const float* x = (const float*)d_in[0];
    const float* y = (const float*)d_in[1];
    float* out      = (float*)d_out;
    float* partials = (float*)d_ws;   // N_MAIN_BLOCKS floats

    ssim_main_kernel<<<N_MAIN_BLOCKS, 256, 0, stream>>>(x, y, partials);
    ssim_reduce_kernel<<<1, 256, 0, stream>>>(partials, out);
}